// Round 6
// baseline (72.631 us; speedup 1.0000x reference)
//
#include <hip/hip_runtime.h>
#include <hip/hip_bf16.h>
#include <math.h>

// B=1024, F=4096, D=32:  s = data@embed, out = sigmoid(gb + data@bias + ||s||^2)
//
// R6: latency-amortized MFMA. Accounting across R1-R5 shows fixed harness overhead
// ~54us (268MB ws-poison fill + restores); our kernels were ~17us. R5's KC=128 gave
// each block only ~11 VMEM/thread before a barrier -> cold-HBM latency exposed per
// block-round (>=2 rounds at 8 blocks/CU). R6: KS=8, KC=512, grid 512 = 2 blocks/CU,
// ALL blocks co-resident (one round); ~32 independent loads/thread in flight.
// Partials 4MB -> 1MB so fm_final is ~1us. MFMA fragment/epilogue mappings identical
// to R5 (verified, absmax 0.0).

#define F_DIM 4096
#define D_DIM 32
#define B_DIM 1024
#define MT 16                 // rows per block
#define KS 8                  // K splits
#define KC 512                // k per block
#define LDA 520               // shorts per LDS row (1040B stride, 16B-aligned, +pad)
#define NW 4

typedef __attribute__((ext_vector_type(8))) short short8;   // MFMA A/B frag (8 bf16)
typedef __attribute__((ext_vector_type(4))) float f32x4;    // MFMA C/D frag

__device__ inline unsigned int pkbf(float a, float b) {     // 2x fp32 -> packed bf16 RNE
    __hip_bfloat162 h = __float22bfloat162_rn(make_float2(a, b));
    union { __hip_bfloat162 h2; unsigned int u; } c; c.h2 = h;
    return c.u;   // low 16 = a, high 16 = b
}

__global__ __launch_bounds__(256, 2) void fm_mfma(const float* __restrict__ data,
                                                  const float* __restrict__ embed,
                                                  const float* __restrict__ bias,
                                                  float* __restrict__ ws_s,
                                                  float* __restrict__ ws_b)
{
    __shared__ short lA [MT][LDA];            // 16x512 bf16 A tile      (16.6 KB)
    __shared__ short lBT[D_DIM][LDA];         // 32x512 bf16 B^T tile    (33.3 KB)
    __shared__ float redCT[NW][2][16][20];    // C frags [nt][col][row]  (10.2 KB)

    const int t  = threadIdx.x;
    const int w  = t >> 6;                    // wave 0..3
    const int l  = t & 63;
    const int mt = blockIdx.x >> 3;           // M-tile 0..63
    const int ks = blockIdx.x & 7;            // K-split 0..7
    const int m0 = mt * MT;
    const int kb = ks * KC;

    // ---- stage A + exact fp32 bias-term: thread owns ONE row r=t>>4, 8 float4 along k ----
    // 16 lanes x 16B = 256B contiguous per row-segment: coalesced.
    {
        const int r = t >> 4;
        const float* rp = data + (size_t)(m0 + r) * F_DIM + kb;
        float bt = 0.f;
        #pragma unroll
        for (int it = 0; it < 8; ++it) {
            const int col = ((t & 15) + it * 16) * 4;      // 0..508 step 4
            const float4 x  = *(const float4*)(rp + col);
            const float4 bv = *(const float4*)(bias + kb + col);   // L1-hit (row-redundant)
            bt = fmaf(x.x, bv.x, bt);
            bt = fmaf(x.y, bv.y, bt);
            bt = fmaf(x.z, bv.z, bt);
            bt = fmaf(x.w, bv.w, bt);
            uint2 pk;
            pk.x = pkbf(x.x, x.y);
            pk.y = pkbf(x.z, x.w);
            *(uint2*)(&lA[r][col]) = pk;                   // ds_write_b64, 8B-aligned
        }
        // reduce bias partial across the 16 lanes sharing this row
        bt += __shfl_xor(bt, 1); bt += __shfl_xor(bt, 2);
        bt += __shfl_xor(bt, 4); bt += __shfl_xor(bt, 8);
        if ((t & 15) == 0) ws_b[(size_t)(m0 + r) * KS + ks] = bt;
    }

    // ---- stage B^T: thread owns d-quad q=t&7, k-range k0..k0+15 ----
    {
        const int q  = t & 7;                 // d-quad 0..7
        const int k0 = (t >> 3) * 16;         // 0..496
        const float* ep = embed + (size_t)(kb + k0) * D_DIM + q * 4;
        float4 e[16];
        #pragma unroll
        for (int j = 0; j < 16; ++j) e[j] = *(const float4*)(ep + (size_t)j * D_DIM);
        #pragma unroll
        for (int c = 0; c < 4; ++c) {
            const int dq = q * 4 + c;
            uint4 u0, u1;
            const float* f = &e[0].x;         // unrolled c -> static component selects
            u0.x = pkbf((&e[ 0].x)[c], (&e[ 1].x)[c]); u0.y = pkbf((&e[ 2].x)[c], (&e[ 3].x)[c]);
            u0.z = pkbf((&e[ 4].x)[c], (&e[ 5].x)[c]); u0.w = pkbf((&e[ 6].x)[c], (&e[ 7].x)[c]);
            u1.x = pkbf((&e[ 8].x)[c], (&e[ 9].x)[c]); u1.y = pkbf((&e[10].x)[c], (&e[11].x)[c]);
            u1.z = pkbf((&e[12].x)[c], (&e[13].x)[c]); u1.w = pkbf((&e[14].x)[c], (&e[15].x)[c]);
            *(uint4*)(&lBT[dq][k0    ]) = u0;  // ds_write_b128, 16B-aligned
            *(uint4*)(&lBT[dq][k0 + 8]) = u1;
            (void)f;
        }
    }
    __syncthreads();

    // ---- MFMA: wave w owns k-slab [w*128, w*128+128): 4 steps x 2 n-tiles ----
    const int quad = l >> 4;
    const int mrow = l & 15;
    f32x4 acc0 = {0.f, 0.f, 0.f, 0.f};
    f32x4 acc1 = {0.f, 0.f, 0.f, 0.f};
    #pragma unroll
    for (int s = 0; s < 4; ++s) {
        const int kk = w * 128 + s * 32 + quad * 8;
        const short8 a  = *(const short8*)(&lA [mrow     ][kk]);
        const short8 b0 = *(const short8*)(&lBT[mrow     ][kk]);   // d = 0..15
        const short8 b1 = *(const short8*)(&lBT[16 + mrow][kk]);   // d = 16..31
        acc0 = __builtin_amdgcn_mfma_f32_16x16x32_bf16(a, b0, acc0, 0, 0, 0);
        acc1 = __builtin_amdgcn_mfma_f32_16x16x32_bf16(a, b1, acc1, 0, 0, 0);
    }

    // ---- K-reduce 4 waves' C frags (C: row=quad*4+reg, col=lane&15; store [col][row]) ----
    *(f32x4*)(&redCT[w][0][mrow][quad * 4]) = acc0;
    *(f32x4*)(&redCT[w][1][mrow][quad * 4]) = acc1;
    __syncthreads();

    #pragma unroll
    for (int h = 0; h < 2; ++h) {
        const int e  = t + h * 256;           // 512 outputs: (nt, r, c)
        const int nt = e >> 8;
        const int r  = (e >> 4) & 15;
        const int c  = e & 15;
        const float v = redCT[0][nt][c][r] + redCT[1][nt][c][r]
                      + redCT[2][nt][c][r] + redCT[3][nt][c][r];
        ws_s[((size_t)(m0 + r) * KS + ks) * D_DIM + nt * 16 + c] = v;
    }
}

// One wave per row: row's KS x 32 partials = 256 floats = 64 float4 (one per lane).
__global__ __launch_bounds__(256, 4) void fm_final(const float* __restrict__ ws_s,
                                                   const float* __restrict__ ws_b,
                                                   const float* __restrict__ gbias,
                                                   float* __restrict__ out)
{
    const int t = threadIdx.x;
    const int w = t >> 6;
    const int l = t & 63;
    const int row = blockIdx.x * 4 + w;

    float4 v = ((const float4*)(ws_s + (size_t)row * KS * D_DIM))[l];  // k=l>>3, d=(l&7)*4
    #pragma unroll
    for (int m = 8; m <= 32; m <<= 1) {       // reduce over k (lanes sharing l&7)
        v.x += __shfl_xor(v.x, m); v.y += __shfl_xor(v.y, m);
        v.z += __shfl_xor(v.z, m); v.w += __shfl_xor(v.w, m);
    }
    float c = 0.f;
    if (l < 8) c = v.x * v.x + v.y * v.y + v.z * v.z + v.w * v.w   // d-quad l
               + ws_b[(size_t)row * KS + l];                       // KS=8 bias partials
    #pragma unroll
    for (int m = 1; m <= 32; m <<= 1) c += __shfl_xor(c, m);
    if (l == 0) {
        const float x = gbias[0] + c;
        out[row] = 1.0f / (1.0f + __expf(-x));
    }
}

extern "C" void kernel_launch(void* const* d_in, const int* in_sizes, int n_in,
                              void* d_out, int out_size, void* d_ws, size_t ws_size,
                              hipStream_t stream) {
    const float* data  = (const float*)d_in[0];
    const float* embed = (const float*)d_in[1];
    const float* bias  = (const float*)d_in[2];
    const float* gb    = (const float*)d_in[3];
    float* out  = (float*)d_out;

    float* ws_s = (float*)d_ws;                                  // 1024*8*32 f = 1 MB
    float* ws_b = (float*)d_ws + (size_t)B_DIM * KS * D_DIM;     // 1024*8 f

    dim3 gridA(64 * KS);     // 512 blocks = 2/CU, all co-resident
    dim3 blockA(256);
    fm_mfma<<<gridA, blockA, 0, stream>>>(data, embed, bias, ws_s, ws_b);

    dim3 gridB(B_DIM / 4);   // 256 blocks, one wave per row
    dim3 blockB(256);
    fm_final<<<gridB, blockB, 0, stream>>>(ws_s, ws_b, gb, out);
}

// Round 7
// 71.686 us; speedup vs baseline: 1.0132x; 1.0132x over previous
//
#include <hip/hip_runtime.h>
#include <hip/hip_bf16.h>
#include <math.h>

// B=1024, F=4096, D=32:  s = data@embed, out = sigmoid(gb + data@bias + ||s||^2)
//
// R7: minimal-serial-structure MFMA. Ledger across R4-R6 says kernels+gaps ~17-20us
// of which ~10-17us is graph-node-gap floor (~25 dispatches/iter). This round strips
// fm_mfma to near its floor: A fragments load DIRECTLY from global (per-lane distinct,
// no LDS staging, no A barrier), issued before B^T staging so cold-HBM latency overlaps
// it; single __syncthreads before MFMA; bias via 1KB LDS. KS=16, KC=256, grid 1024
// (4/CU, one full round). Fragment/epilogue mappings verified R4-R6 (absmax 0.0).

#define F_DIM 4096
#define D_DIM 32
#define B_DIM 1024
#define MT 16                 // rows per block
#define KS 16                 // K splits
#define KC 256                // k per block
#define LDA 264               // shorts per lBT row (528B stride; b128 banks <=2-way)
#define NW 4

typedef __attribute__((ext_vector_type(8))) short short8;   // MFMA A/B frag (8 bf16)
typedef __attribute__((ext_vector_type(4))) float f32x4;    // MFMA C/D frag

__device__ inline unsigned int pkbf(float a, float b) {     // 2x fp32 -> packed bf16 RNE
    __hip_bfloat162 h = __float22bfloat162_rn(make_float2(a, b));
    union { __hip_bfloat162 h2; unsigned int u; } c; c.h2 = h;
    return c.u;   // low 16 = a, high 16 = b
}

__device__ inline short8 cvt_frag(float4 lo, float4 hi) {   // 8 fp32 -> A-frag (4 cvt_pk)
    union { short8 s; uint4 u; } c;
    c.u.x = pkbf(lo.x, lo.y);
    c.u.y = pkbf(lo.z, lo.w);
    c.u.z = pkbf(hi.x, hi.y);
    c.u.w = pkbf(hi.z, hi.w);
    return c.s;
}

__global__ __launch_bounds__(256, 4) void fm_mfma(const float* __restrict__ data,
                                                  const float* __restrict__ embed,
                                                  const float* __restrict__ bias,
                                                  float* __restrict__ ws_s,
                                                  float* __restrict__ ws_b)
{
    __shared__ short lBT[D_DIM][LDA];         // 32x256 bf16 B^T tile (16.5 KB)
    __shared__ float lBias[KC];               // 1 KB
    __shared__ float redCT[NW][2][16][20];    // C frags [nt][col][row] (10 KB)
    __shared__ float red_bt[NW][16];          // bias partials per wave (256 B)

    const int t    = threadIdx.x;
    const int w    = t >> 6;                  // wave 0..3
    const int l    = t & 63;
    const int quad = l >> 4;
    const int mrow = l & 15;
    const int mt   = blockIdx.x >> 4;         // M-tile 0..63
    const int ks   = blockIdx.x & 15;         // K-split 0..15
    const int m0   = mt * MT;
    const int kb   = ks * KC;

    // ---- A-fragment loads FIRST (direct from global, per-lane distinct) ----
    // lane(q,mrow): data[m0+mrow][kb + w*64 + s*32 + q*8 ..+7], s=0,1.
    // Per inst: 16 rows x 4 quads cover dense 128B lines. Issued before staging
    // so the cold-HBM latency overlaps the B^T stage below.
    const float* ap = data + (size_t)(m0 + mrow) * F_DIM + kb + w * 64 + quad * 8;
    const float4 xa = *(const float4*)(ap);
    const float4 xb = *(const float4*)(ap + 4);
    const float4 xc = *(const float4*)(ap + 32);
    const float4 xd = *(const float4*)(ap + 36);

    // ---- stage B^T: thread owns d-pair (t&15)*2, 16 consecutive k ----
    {
        const int d2 = (t & 15) * 2;
        const int k0 = (t >> 4) * 16;         // 0..240
        const float* ep = embed + (size_t)(kb + k0) * D_DIM + d2;
        float2 e[16];
        #pragma unroll
        for (int j = 0; j < 16; ++j) e[j] = *(const float2*)(ep + (size_t)j * D_DIM);
        uint4 u;
        u.x = pkbf(e[0].x, e[1].x); u.y = pkbf(e[2].x, e[3].x);
        u.z = pkbf(e[4].x, e[5].x); u.w = pkbf(e[6].x, e[7].x);
        *(uint4*)(&lBT[d2][k0]) = u;
        u.x = pkbf(e[ 8].x, e[ 9].x); u.y = pkbf(e[10].x, e[11].x);
        u.z = pkbf(e[12].x, e[13].x); u.w = pkbf(e[14].x, e[15].x);
        *(uint4*)(&lBT[d2][k0 + 8]) = u;
        u.x = pkbf(e[0].y, e[1].y); u.y = pkbf(e[2].y, e[3].y);
        u.z = pkbf(e[4].y, e[5].y); u.w = pkbf(e[6].y, e[7].y);
        *(uint4*)(&lBT[d2 + 1][k0]) = u;
        u.x = pkbf(e[ 8].y, e[ 9].y); u.y = pkbf(e[10].y, e[11].y);
        u.z = pkbf(e[12].y, e[13].y); u.w = pkbf(e[14].y, e[15].y);
        *(uint4*)(&lBT[d2 + 1][k0 + 8]) = u;
    }
    lBias[t] = bias[kb + t];                  // KC == blockDim, coalesced
    __syncthreads();

    // ---- bias term (exact fp32) from the already-loaded A values ----
    const float* bp = &lBias[w * 64 + quad * 8];
    const float4 bv0 = *(const float4*)(bp);
    const float4 bv1 = *(const float4*)(bp + 4);
    const float4 bv2 = *(const float4*)(bp + 32);
    const float4 bv3 = *(const float4*)(bp + 36);
    float bt = xa.x * bv0.x;
    bt = fmaf(xa.y, bv0.y, bt); bt = fmaf(xa.z, bv0.z, bt); bt = fmaf(xa.w, bv0.w, bt);
    bt = fmaf(xb.x, bv1.x, bt); bt = fmaf(xb.y, bv1.y, bt);
    bt = fmaf(xb.z, bv1.z, bt); bt = fmaf(xb.w, bv1.w, bt);
    bt = fmaf(xc.x, bv2.x, bt); bt = fmaf(xc.y, bv2.y, bt);
    bt = fmaf(xc.z, bv2.z, bt); bt = fmaf(xc.w, bv2.w, bt);
    bt = fmaf(xd.x, bv3.x, bt); bt = fmaf(xd.y, bv3.y, bt);
    bt = fmaf(xd.z, bv3.z, bt); bt = fmaf(xd.w, bv3.w, bt);
    bt += __shfl_xor(bt, 16);                 // reduce over quads (same mrow)
    bt += __shfl_xor(bt, 32);
    if (l < 16) red_bt[w][l] = bt;            // lanes 0..15: mrow = l

    // ---- MFMA: 2 K-steps x 2 n-tiles ----
    const short8 a0 = cvt_frag(xa, xb);
    const short8 a1 = cvt_frag(xc, xd);
    const int kk = w * 64 + quad * 8;
    const short8 b00 = *(const short8*)(&lBT[mrow     ][kk     ]);
    const short8 b01 = *(const short8*)(&lBT[16 + mrow][kk     ]);
    const short8 b10 = *(const short8*)(&lBT[mrow     ][kk + 32]);
    const short8 b11 = *(const short8*)(&lBT[16 + mrow][kk + 32]);
    const f32x4 z = {0.f, 0.f, 0.f, 0.f};
    f32x4 acc0 = __builtin_amdgcn_mfma_f32_16x16x32_bf16(a0, b00, z,    0, 0, 0);
    f32x4 acc1 = __builtin_amdgcn_mfma_f32_16x16x32_bf16(a0, b01, z,    0, 0, 0);
    acc0       = __builtin_amdgcn_mfma_f32_16x16x32_bf16(a1, b10, acc0, 0, 0, 0);
    acc1       = __builtin_amdgcn_mfma_f32_16x16x32_bf16(a1, b11, acc1, 0, 0, 0);

    // ---- K-reduce 4 waves (C: row=quad*4+reg, col=lane&15; stored [col][row]) ----
    *(f32x4*)(&redCT[w][0][mrow][quad * 4]) = acc0;
    *(f32x4*)(&redCT[w][1][mrow][quad * 4]) = acc1;
    __syncthreads();

    if (t < 16)
        ws_b[(size_t)(m0 + t) * KS + ks] =
            red_bt[0][t] + red_bt[1][t] + red_bt[2][t] + red_bt[3][t];

    #pragma unroll
    for (int h = 0; h < 2; ++h) {
        const int e  = t + h * 256;           // 512 outputs: (nt, r, c)
        const int nt = e >> 8;
        const int r  = (e >> 4) & 15;
        const int c  = e & 15;
        const float v = redCT[0][nt][c][r] + redCT[1][nt][c][r]
                      + redCT[2][nt][c][r] + redCT[3][nt][c][r];
        ws_s[((size_t)(m0 + r) * KS + ks) * D_DIM + nt * 16 + c] = v;
    }
}

// One wave per row: row's KS x 32 partials = 512 floats = 128 float4 (2 per lane).
__global__ __launch_bounds__(256, 4) void fm_final(const float* __restrict__ ws_s,
                                                   const float* __restrict__ ws_b,
                                                   const float* __restrict__ gbias,
                                                   float* __restrict__ out)
{
    const int t = threadIdx.x;
    const int w = t >> 6;
    const int l = t & 63;
    const int row = blockIdx.x * 4 + w;

    const float4* p = (const float4*)(ws_s + (size_t)row * KS * D_DIM);
    // float4 index i: k = i>>3, d-quad = i&7.  l and l+64 share d-quad, k differs by 8.
    float4 v = p[l];
    const float4 v2 = p[l + 64];
    v.x += v2.x; v.y += v2.y; v.z += v2.z; v.w += v2.w;
    #pragma unroll
    for (int m = 8; m <= 32; m <<= 1) {       // reduce over k (xor on bits 3..5 of l)
        v.x += __shfl_xor(v.x, m); v.y += __shfl_xor(v.y, m);
        v.z += __shfl_xor(v.z, m); v.w += __shfl_xor(v.w, m);
    }
    float c = 0.f;
    if (l < 8)  c = v.x * v.x + v.y * v.y + v.z * v.z + v.w * v.w;  // d-quad l
    if (l < 16) c += ws_b[(size_t)row * KS + l];                    // KS=16 bias partials
    #pragma unroll
    for (int m = 1; m <= 32; m <<= 1) c += __shfl_xor(c, m);
    if (l == 0) {
        const float x = gbias[0] + c;
        out[row] = 1.0f / (1.0f + __expf(-x));
    }
}

extern "C" void kernel_launch(void* const* d_in, const int* in_sizes, int n_in,
                              void* d_out, int out_size, void* d_ws, size_t ws_size,
                              hipStream_t stream) {
    const float* data  = (const float*)d_in[0];
    const float* embed = (const float*)d_in[1];
    const float* bias  = (const float*)d_in[2];
    const float* gb    = (const float*)d_in[3];
    float* out  = (float*)d_out;

    float* ws_s = (float*)d_ws;                                  // 1024*16*32 f = 2 MB
    float* ws_b = (float*)d_ws + (size_t)B_DIM * KS * D_DIM;     // 1024*16 f

    dim3 gridA(64 * KS);     // 1024 blocks = 4/CU, one full round
    dim3 blockA(256);
    fm_mfma<<<gridA, blockA, 0, stream>>>(data, embed, bias, ws_s, ws_b);

    dim3 gridB(B_DIM / 4);   // 256 blocks, one wave per row
    dim3 blockB(256);
    fm_final<<<gridB, blockB, 0, stream>>>(ws_s, ws_b, gb, out);
}